// Round 4
// baseline (75.118 us; speedup 1.0000x reference)
//
#include <hip/hip_runtime.h>

#define NORB 96
#define NN 9216  // 96*96

typedef float f32x4 __attribute__((ext_vector_type(4)));

// ---------------------------------------------------------------------------
// prep kernel: blocks 0..95  -> L = X @ H_core @ X^T (row i) + zero Km row i
//              blocks 96..191-> LayerNorm + QKV projection (row i)
// ---------------------------------------------------------------------------
__global__ __launch_bounds__(192) void prep_kernel(
    const float* __restrict__ X, const float* __restrict__ Hc,
    const float* __restrict__ x, const float* __restrict__ ln_s,
    const float* __restrict__ ln_b, const float* __restrict__ Wqkv,
    float* __restrict__ Lm, float* __restrict__ Km, float* __restrict__ qkv) {
  const int blk = blockIdx.x;
  const int t = threadIdx.x;  // 0..191
  if (blk < 96) {
    const int i = blk;
    __shared__ float Xs[NN];
    __shared__ float tmp[NORB];
    for (int f = t; f < NN; f += 192) Xs[f] = X[f];
    if (t < NORB) Km[i * NORB + t] = 0.f;
    __syncthreads();
    if (t < NORB) {
      float acc = 0.f;
      for (int m = 0; m < NORB; ++m) acc += Xs[i * NORB + m] * Hc[m * NORB + t];
      tmp[t] = acc;
    }
    __syncthreads();
    if (t < NORB) {
      float acc = 0.f;
      for (int k = 0; k < NORB; ++k) acc += tmp[k] * Xs[t * NORB + k];
      Lm[i * NORB + t] = acc;
    }
  } else {
    const int i = blk - 96;
    __shared__ float xn[128];
    __shared__ float red[3];
    float v = (t < 128) ? x[i * 128 + t] : 0.f;
    float s = v;
#pragma unroll
    for (int off = 32; off; off >>= 1) s += __shfl_down(s, off);
    if ((t & 63) == 0) red[t >> 6] = s;
    __syncthreads();
    const float mu = (red[0] + red[1] + red[2]) * (1.f / 128.f);
    __syncthreads();
    const float dv = (t < 128) ? (v - mu) : 0.f;
    s = dv * dv;
#pragma unroll
    for (int off = 32; off; off >>= 1) s += __shfl_down(s, off);
    if ((t & 63) == 0) red[t >> 6] = s;
    __syncthreads();
    const float var = (red[0] + red[1] + red[2]) * (1.f / 128.f);
    if (t < 128) xn[t] = dv * rsqrtf(var + 1e-6f) * ln_s[t] + ln_b[t];
    __syncthreads();
#pragma unroll
    for (int jj = 0; jj < 2; ++jj) {
      const int j = t + jj * 192;
      float acc = 0.f;
      for (int c = 0; c < 128; ++c) acc += xn[c] * Wqkv[c * 384 + j];
      qkv[i * 384 + j] = acc;
    }
  }
}

// ---------------------------------------------------------------------------
// Streaming J/K pass: TWO slabs per block (a0,b),(a1,b), 384 threads.
// 12 outstanding NT float4 loads/thread, 1 vmem instr per 16B, no mid-stream
// barriers. Thread (x=t%24, y=t/24): d = 4x..4x+3, c = y + 16k.
// ---------------------------------------------------------------------------
__global__ __launch_bounds__(384) void jk_kernel(
    const float* __restrict__ eri, const float* __restrict__ P,
    float* __restrict__ Jm, float* __restrict__ Km) {
  const int blk = blockIdx.x;  // 0..4607
  const int b = blk % NORB;
  const int ap = blk / NORB;  // 0..47
  const int a0 = 2 * ap, a1 = a0 + 1;
  const int t = threadIdx.x;
  const int x = t % 24;
  const int y = t / 24;  // 0..15
  const f32x4* __restrict__ slab0 =
      (const f32x4*)(eri + (size_t)(a0 * NORB + b) * NN);
  const f32x4* __restrict__ slab1 =
      (const f32x4*)(eri + (size_t)(a1 * NORB + b) * NN);
  const f32x4* __restrict__ P4 = (const f32x4*)P;

  __shared__ float pa_sh[2][NORB];
  __shared__ float klp[16][NORB];
  __shared__ float js[2][6];

  if (t < NORB) pa_sh[0][t] = P[a0 * NORB + t];
  else if (t < 2 * NORB) pa_sh[1][t - NORB] = P[a1 * NORB + (t - NORB)];

  f32x4 pvr[6];
#pragma unroll
  for (int k = 0; k < 6; ++k) pvr[k] = P4[t + 384 * k];
  __syncthreads();

  float jp0 = 0.f, jp1 = 0.f;
  f32x4 kacc = {0.f, 0.f, 0.f, 0.f};
#pragma unroll
  for (int k = 0; k < 6; ++k) {
    const f32x4 v0 = __builtin_nontemporal_load(&slab0[t + 384 * k]);
    const f32x4 v1 = __builtin_nontemporal_load(&slab1[t + 384 * k]);
    const float pa0 = pa_sh[0][y + 16 * k];
    const float pa1 = pa_sh[1][y + 16 * k];
    jp0 += v0.x * pvr[k].x + v0.y * pvr[k].y + v0.z * pvr[k].z + v0.w * pvr[k].w;
    jp1 += v1.x * pvr[k].x + v1.y * pvr[k].y + v1.z * pvr[k].z + v1.w * pvr[k].w;
    kacc += pa0 * v0 + pa1 * v1;
  }

  klp[y][4 * x + 0] = kacc.x;
  klp[y][4 * x + 1] = kacc.y;
  klp[y][4 * x + 2] = kacc.z;
  klp[y][4 * x + 3] = kacc.w;
#pragma unroll
  for (int off = 32; off; off >>= 1) {
    jp0 += __shfl_down(jp0, off);
    jp1 += __shfl_down(jp1, off);
  }
  if ((t & 63) == 0) {
    js[0][t >> 6] = jp0;
    js[1][t >> 6] = jp1;
  }
  __syncthreads();
  if (t < 2) {
    const float* j6 = js[t];
    Jm[(a0 + t) * NORB + b] = j6[0] + j6[1] + j6[2] + j6[3] + j6[4] + j6[5];
  }
  if (t < NORB) {
    float kk = 0.f;
#pragma unroll
    for (int yy = 0; yy < 16; ++yy) kk += klp[yy][t];
    atomicAdd(&Km[b * NORB + t], kk);
  }
}

// ---------------------------------------------------------------------------
// Fused biased attention + output projection. One block per row i (96 blocks,
// 256 threads). Thread (h=t>>4, jg=t&15) computes 6 scores (j = jg+16m);
// softmax via 16-lane subgroup shuffles; PV + Wout projection with 128 thr.
// ---------------------------------------------------------------------------
__global__ __launch_bounds__(256) void attn_proj_kernel(
    const float* __restrict__ qkv, const float* __restrict__ Hc,
    const float* __restrict__ Jm, const float* __restrict__ Km,
    const float* __restrict__ Lm, const float* __restrict__ Wout,
    const float* __restrict__ bout, float* __restrict__ y) {
  const int i = blockIdx.x;
  const int t = threadIdx.x;  // 0..255
  __shared__ float qs[128];
  __shared__ float ps[16][97];  // pad 97: PV reads bank-conflict-free
  __shared__ float aout_sh[128];

  if (t < 128) qs[t] = qkv[i * 384 + t];
  __syncthreads();

  const int h = t >> 4;   // 0..15
  const int jg = t & 15;  // 0..15
  float sc[6];
#pragma unroll
  for (int m = 0; m < 6; ++m) {
    const int j = jg + 16 * m;
    const float* kr = qkv + j * 384 + 128 + h * 8;
    float d = 0.f;
#pragma unroll
    for (int dd = 0; dd < 8; ++dd) d += qs[h * 8 + dd] * kr[dd];
    d *= 0.3535533905932738f;  // 1/sqrt(8)
    const int ij = i * NORB + j;
    if (h < 2) d += Hc[ij];
    else if (h < 4) d += Jm[ij] - 0.5f * Km[ij];
    else if (h < 6) d += Lm[ij];
    sc[m] = d;
  }
  float mx = sc[0];
#pragma unroll
  for (int m = 1; m < 6; ++m) mx = fmaxf(mx, sc[m]);
#pragma unroll
  for (int off = 8; off; off >>= 1) mx = fmaxf(mx, __shfl_xor(mx, off, 16));
  float sm = 0.f;
#pragma unroll
  for (int m = 0; m < 6; ++m) {
    sc[m] = __expf(sc[m] - mx);
    sm += sc[m];
  }
#pragma unroll
  for (int off = 8; off; off >>= 1) sm += __shfl_xor(sm, off, 16);
  const float inv = 1.f / sm;
#pragma unroll
  for (int m = 0; m < 6; ++m) ps[h][jg + 16 * m] = sc[m] * inv;
  __syncthreads();

  if (t < 128) {
    const int h2 = t >> 3;  // c = t
    float acc = 0.f;
#pragma unroll 8
    for (int j = 0; j < NORB; ++j) acc += ps[h2][j] * qkv[j * 384 + 256 + t];
    aout_sh[t] = acc;
  }
  __syncthreads();
  if (t < 128) {
    float acc = bout[t];
#pragma unroll 8
    for (int c = 0; c < 128; ++c) acc += aout_sh[c] * Wout[c * 128 + t];
    y[i * 128 + t] = acc;
  }
}

// ---------------------------------------------------------------------------
extern "C" void kernel_launch(void* const* d_in, const int* in_sizes, int n_in,
                              void* d_out, int out_size, void* d_ws,
                              size_t ws_size, hipStream_t stream) {
  const float* x    = (const float*)d_in[0];
  const float* Hc   = (const float*)d_in[1];
  const float* X    = (const float*)d_in[2];
  const float* eri  = (const float*)d_in[3];
  const float* P    = (const float*)d_in[4];
  const float* ln_s = (const float*)d_in[5];
  const float* ln_b = (const float*)d_in[6];
  const float* Wqkv = (const float*)d_in[7];
  const float* Wout = (const float*)d_in[8];
  const float* bout = (const float*)d_in[9];
  float* y = (float*)d_out;

  float* ws  = (float*)d_ws;
  float* Jm  = ws;             // 9216
  float* Km  = ws + NN;        // 9216
  float* Lm  = ws + 2 * NN;    // 9216
  float* qkv = ws + 3 * NN;    // 96*384

  // prep: L rows + Km zeroing (blocks 0-95), LN+QKV (blocks 96-191)
  prep_kernel<<<192, 192, 0, stream>>>(X, Hc, x, ln_s, ln_b, Wqkv, Lm, Km, qkv);

  // dominant pass: stream eri once (2 slabs per block), produce J and K
  jk_kernel<<<4608, 384, 0, stream>>>(eri, P, Jm, Km);

  // fused biased attention + output projection
  attn_proj_kernel<<<NORB, 256, 0, stream>>>(qkv, Hc, Jm, Km, Lm, Wout, bout, y);
}

// Round 5
// 73.306 us; speedup vs baseline: 1.0247x; 1.0247x over previous
//
#include <hip/hip_runtime.h>

#define NORB 96
#define NN 9216  // 96*96

typedef float f32x4 __attribute__((ext_vector_type(4)));

// ---------------------------------------------------------------------------
// Fused mega-kernel, 384 threads/block:
//   blocks 0..95    : L = X @ H_core @ X^T (row i), tiny-LDS variant
//   blocks 96..191  : LayerNorm + QKV projection (row i)
//   blocks 192..9407: jk streaming pass, one (a,b) slab per block (v2 config)
//                     -> Jm[ab], Kpart[a][b][0..95] (plain stores, no atomics)
// ---------------------------------------------------------------------------
__global__ __launch_bounds__(384) void mega_kernel(
    const float* __restrict__ eri, const float* __restrict__ P,
    const float* __restrict__ X, const float* __restrict__ Hc,
    const float* __restrict__ x, const float* __restrict__ ln_s,
    const float* __restrict__ ln_b, const float* __restrict__ Wqkv,
    float* __restrict__ Jm, float* __restrict__ Kpart,
    float* __restrict__ Lm, float* __restrict__ qkv) {
  const int blk = blockIdx.x;
  const int t = threadIdx.x;  // 0..383

  if (blk < 96) {
    // ---- L row i ----
    const int i = blk;
    __shared__ float xrow[NORB];
    __shared__ float tmp[NORB];
    if (t < NORB) xrow[t] = X[i * NORB + t];
    __syncthreads();
    if (t < NORB) {
      float acc = 0.f;
      for (int m = 0; m < NORB; ++m) acc += xrow[m] * Hc[m * NORB + t];
      tmp[t] = acc;
    }
    __syncthreads();
    if (t < NORB) {
      float acc = 0.f;
      for (int k = 0; k < NORB; ++k) acc += tmp[k] * X[t * NORB + k];
      Lm[i * NORB + t] = acc;
    }
    return;
  }
  if (blk < 192) {
    // ---- LayerNorm + QKV row i ----
    const int i = blk - 96;
    __shared__ float xn[128];
    __shared__ float red[2];
    float v = (t < 128) ? x[i * 128 + t] : 0.f;
    float s = v;
#pragma unroll
    for (int off = 32; off; off >>= 1) s += __shfl_down(s, off);
    if (t == 0 || t == 64) red[t >> 6] = s;
    __syncthreads();
    const float mu = (red[0] + red[1]) * (1.f / 128.f);
    __syncthreads();
    const float dv = (t < 128) ? (v - mu) : 0.f;
    s = dv * dv;
#pragma unroll
    for (int off = 32; off; off >>= 1) s += __shfl_down(s, off);
    if (t == 0 || t == 64) red[t >> 6] = s;
    __syncthreads();
    const float var = (red[0] + red[1]) * (1.f / 128.f);
    if (t < 128) xn[t] = dv * rsqrtf(var + 1e-6f) * ln_s[t] + ln_b[t];
    __syncthreads();
    float acc = 0.f;
    for (int c = 0; c < 128; ++c) acc += xn[c] * Wqkv[c * 384 + t];
    qkv[i * 384 + t] = acc;
    return;
  }

  // ---- jk slab (v2 config: 6-deep NT loads, no mid-stream barriers) ----
  const int ab = blk - 192;
  const int a = ab / NORB;
  const int b = ab - a * NORB;
  const int x24 = t % 24;
  const int y = t / 24;  // 0..15
  const f32x4* __restrict__ slab4 = (const f32x4*)(eri + (size_t)ab * NN);
  const f32x4* __restrict__ P4 = (const f32x4*)P;

  __shared__ float pa_sh[NORB];
  __shared__ float klp[16][NORB];
  __shared__ float js[6];

  if (t < NORB) pa_sh[t] = P[a * NORB + t];

  f32x4 pvr[6];
#pragma unroll
  for (int k = 0; k < 6; ++k) pvr[k] = P4[t + 384 * k];
  __syncthreads();

  float jp = 0.f, k0 = 0.f, k1 = 0.f, k2 = 0.f, k3 = 0.f;
#pragma unroll
  for (int k = 0; k < 6; ++k) {
    const f32x4 v = __builtin_nontemporal_load(&slab4[t + 384 * k]);
    const float pa = pa_sh[y + 16 * k];
    jp += v.x * pvr[k].x + v.y * pvr[k].y + v.z * pvr[k].z + v.w * pvr[k].w;
    k0 += pa * v.x;
    k1 += pa * v.y;
    k2 += pa * v.z;
    k3 += pa * v.w;
  }

  klp[y][4 * x24 + 0] = k0;
  klp[y][4 * x24 + 1] = k1;
  klp[y][4 * x24 + 2] = k2;
  klp[y][4 * x24 + 3] = k3;
#pragma unroll
  for (int off = 32; off; off >>= 1) jp += __shfl_down(jp, off);
  if ((t & 63) == 0) js[t >> 6] = jp;
  __syncthreads();
  if (t == 0) Jm[ab] = js[0] + js[1] + js[2] + js[3] + js[4] + js[5];
  if (t < NORB) {
    float kk = 0.f;
#pragma unroll
    for (int yy = 0; yy < 16; ++yy) kk += klp[yy][t];
    Kpart[(size_t)a * NN + b * NORB + t] = kk;  // plain store, no init needed
  }
}

// ---------------------------------------------------------------------------
// Fused K-reduce + biased attention + output projection. One block per row i
// (96 blocks, 256 threads). Prologue: Km row i = sum_a Kpart[a][i][*].
// ---------------------------------------------------------------------------
__global__ __launch_bounds__(256) void attn_proj_kernel(
    const float* __restrict__ qkv, const float* __restrict__ Hc,
    const float* __restrict__ Jm, const float* __restrict__ Kpart,
    const float* __restrict__ Lm, const float* __restrict__ Wout,
    const float* __restrict__ bout, float* __restrict__ y) {
  const int i = blockIdx.x;
  const int t = threadIdx.x;  // 0..255
  __shared__ float qs[128];
  __shared__ float kmrow[NORB];
  __shared__ float ps[16][97];  // pad 97: PV reads bank-conflict-free
  __shared__ float aout_sh[128];

  if (t < 128) qs[t] = qkv[i * 384 + t];
  if (t < NORB) {
    float kk = 0.f;
#pragma unroll 8
    for (int a = 0; a < NORB; ++a) kk += Kpart[(size_t)a * NN + i * NORB + t];
    kmrow[t] = kk;
  }
  __syncthreads();

  const int h = t >> 4;   // 0..15
  const int jg = t & 15;  // 0..15
  float sc[6];
#pragma unroll
  for (int m = 0; m < 6; ++m) {
    const int j = jg + 16 * m;
    const float* kr = qkv + j * 384 + 128 + h * 8;
    float d = 0.f;
#pragma unroll
    for (int dd = 0; dd < 8; ++dd) d += qs[h * 8 + dd] * kr[dd];
    d *= 0.3535533905932738f;  // 1/sqrt(8)
    const int ij = i * NORB + j;
    if (h < 2) d += Hc[ij];
    else if (h < 4) d += Jm[ij] - 0.5f * kmrow[j];
    else if (h < 6) d += Lm[ij];
    sc[m] = d;
  }
  float mx = sc[0];
#pragma unroll
  for (int m = 1; m < 6; ++m) mx = fmaxf(mx, sc[m]);
#pragma unroll
  for (int off = 8; off; off >>= 1) mx = fmaxf(mx, __shfl_xor(mx, off, 16));
  float sm = 0.f;
#pragma unroll
  for (int m = 0; m < 6; ++m) {
    sc[m] = __expf(sc[m] - mx);
    sm += sc[m];
  }
#pragma unroll
  for (int off = 8; off; off >>= 1) sm += __shfl_xor(sm, off, 16);
  const float inv = 1.f / sm;
#pragma unroll
  for (int m = 0; m < 6; ++m) ps[h][jg + 16 * m] = sc[m] * inv;
  __syncthreads();

  if (t < 128) {
    const int h2 = t >> 3;
    float acc = 0.f;
#pragma unroll 8
    for (int j = 0; j < NORB; ++j) acc += ps[h2][j] * qkv[j * 384 + 256 + t];
    aout_sh[t] = acc;
  }
  __syncthreads();
  if (t < 128) {
    float acc = bout[t];
#pragma unroll 8
    for (int c = 0; c < 128; ++c) acc += aout_sh[c] * Wout[c * 128 + t];
    y[i * 128 + t] = acc;
  }
}

// ---------------------------------------------------------------------------
extern "C" void kernel_launch(void* const* d_in, const int* in_sizes, int n_in,
                              void* d_out, int out_size, void* d_ws,
                              size_t ws_size, hipStream_t stream) {
  const float* x    = (const float*)d_in[0];
  const float* Hc   = (const float*)d_in[1];
  const float* X    = (const float*)d_in[2];
  const float* eri  = (const float*)d_in[3];
  const float* P    = (const float*)d_in[4];
  const float* ln_s = (const float*)d_in[5];
  const float* ln_b = (const float*)d_in[6];
  const float* Wqkv = (const float*)d_in[7];
  const float* Wout = (const float*)d_in[8];
  const float* bout = (const float*)d_in[9];
  float* y = (float*)d_out;

  float* ws    = (float*)d_ws;
  float* Jm    = ws;                  // 9216
  float* Lm    = ws + NN;             // 9216
  float* qkv   = ws + 2 * NN;         // 96*384 = 36864
  float* Kpart = ws + 2 * NN + 36864; // 96*9216 = 884736 (3.4 MB)

  // one dispatch: prep (192 blocks) + eri stream (9216 blocks)
  mega_kernel<<<192 + NN, 384, 0, stream>>>(eri, P, X, Hc, x, ln_s, ln_b,
                                            Wqkv, Jm, Kpart, Lm, qkv);

  // K-reduce + biased attention + output projection
  attn_proj_kernel<<<NORB, 256, 0, stream>>>(qkv, Hc, Jm, Kpart, Lm, Wout,
                                             bout, y);
}